// Round 3
// baseline (755.791 us; speedup 1.0000x reference)
//
#include <hip/hip_runtime.h>
#include <hip/hip_bf16.h>
#include <cstdint>

typedef __attribute__((ext_vector_type(8))) short s8vec;
typedef __attribute__((ext_vector_type(4))) float f4vec;

#define DEV __device__ __forceinline__

constexpr int Bn = 2, Sn = 2048, HIDn = 4096, Hn = 32, KVn = 8, Dn = 128;

typedef const __attribute__((address_space(1))) void gvoid_t;
typedef __attribute__((address_space(3))) void lvoid_t;

DEV void async_ld16(const void* g, void* l) {
  __builtin_amdgcn_global_load_lds((gvoid_t*)g, (lvoid_t*)l, 16, 0, 0);
}

DEV f4vec mfma16(s8vec a, s8vec b, f4vec c) {
  return __builtin_amdgcn_mfma_f32_16x16x32_bf16(a, b, c, 0, 0, 0);
}

// ---------------------------------------------------------------------------
// Fused fp32 -> bf16 cast for all 5 tensors in one launch.
// ---------------------------------------------------------------------------
__global__ void cvt_all(const float* __restrict__ x, const float* __restrict__ qw,
                        const float* __restrict__ kw, const float* __restrict__ vw,
                        const float* __restrict__ ow,
                        __hip_bfloat16* __restrict__ xb, __hip_bfloat16* __restrict__ qwb,
                        __hip_bfloat16* __restrict__ kwb, __hip_bfloat16* __restrict__ vwb,
                        __hip_bfloat16* __restrict__ owb) {
  const int i = blockIdx.x * 256 + threadIdx.x;
  const float* src; __hip_bfloat16* dst; int off;
  if (i < 4194304)       { src = x;  dst = xb;  off = i; }
  else if (i < 8388608)  { src = qw; dst = qwb; off = i - 4194304; }
  else if (i < 9437184)  { src = kw; dst = kwb; off = i - 8388608; }
  else if (i < 10485760) { src = vw; dst = vwb; off = i - 9437184; }
  else                   { src = ow; dst = owb; off = i - 10485760; }
  float4 f = ((const float4*)src)[off];
  union { __hip_bfloat16 h[4]; uint2 u; } cv;
  cv.h[0] = __float2bfloat16(f.x);
  cv.h[1] = __float2bfloat16(f.y);
  cv.h[2] = __float2bfloat16(f.z);
  cv.h[3] = __float2bfloat16(f.w);
  ((uint2*)dst)[off] = cv.u;
}

// ---------------------------------------------------------------------------
// GEMM-BT core v4: C[M,N] = A[M,K]*B[N,K]^T.  8-phase m201-style schedule.
// 256x256 tile, BK=64, 512 threads = 8 waves (2M x 4N), per-wave 128x64 out.
// LDS: per operand a 4-slot ring of K-HALVES (256 rows x 32 k-elems = 16 KB),
//      slot = khalf_index & 3.  Total 128 KB.
// Per K-tile: 4 phases (ks x m-group), each = {ds_read 4-8 b128; stage ONE
// half (2 gload_lds); barrier; lgkm(0)+sched_barrier; setprio(1); 16 MFMA;
// setprio(0); [vmcnt(10) at P1/P3]; barrier}.  Each staged half gets 6-7
// phases (~1000 cy) of latency cover; vmcnt(10) = 5 halves in flight, never
// drains in steady state (tail: 8/4 -> 0, ledger-verified).
// Swizzle both-sides: physical chunk p of row r holds logical chunk
// p ^ ((r>>1)&3); stager pre-XORs the global column, reader XORs its quad.
// 16 lanes of a frag-read hit all 8 16B-cols exactly twice = minimal alias
// (same class as round-2's measured-zero-conflict layout).
// ---------------------------------------------------------------------------
template <typename EpiF>
DEV void gemm_bt_body(const __hip_bfloat16* A, const __hip_bfloat16* Bw, int K,
                      long m0, long n0, EpiF epi) {
  __shared__ __hip_bfloat16 As[4][256 * 32];
  __shared__ __hip_bfloat16 Bs[4][256 * 32];
  const int t = threadIdx.x;       // 0..511
  const int w = t >> 6, l = t & 63;
  const int lane15 = l & 15, quad = l >> 4;
  const int wm = (w >> 2) << 7;    // 0,128
  const int wn = (w & 3) << 6;     // 0,64,128,192

  f4vec acc[8][4] = {};

  // ---- staging addressing ----
  // thread t covers rows srow, srow+128; physical chunk t&3.
  // source column pre-swizzled: logical chunk = (t&3) ^ ((row>>1)&3)
  // (identical for row and row+128 since 128 ≡ 0 mod 4 after >>1).
  const int srow = t >> 2;                      // 0..127
  const int scol = ((t & 3) ^ ((srow >> 1) & 3)) << 3;  // elems
  const __hip_bfloat16* gA = A + (m0 + srow) * (long)K + scol;
  const __hip_bfloat16* gB = Bw + (n0 + srow) * (long)K + scol;
  const long half128 = (long)128 * K;

  auto stageA = [&](int n) {  // khalf index n: k-elems n*32..n*32+31
    char* d = (char*)As + ((n & 3) << 14) + t * 16;
    const __hip_bfloat16* g = gA + (long)n * 32;
    async_ld16(g, d);
    async_ld16(g + half128, d + 8192);
  };
  auto stageB = [&](int n) {
    char* d = (char*)Bs + ((n & 3) << 14) + t * 16;
    const __hip_bfloat16* g = gB + (long)n * 32;
    async_ld16(g, d);
    async_ld16(g + half128, d + 8192);
  };

  // ---- fragment read addressing ----
  // row = wm/wn + i*16 + lane15; byte = row*64 + ((quad ^ ((row>>1)&3))<<4);
  // (row>>1)&3 == (lane15>>1)&3 for all frags.
  const int rswz = (quad ^ ((lane15 >> 1) & 3)) << 4;
  const int aoff = (wm + lane15) * 64 + rswz;
  const int boff = (wn + lane15) * 64 + rswz;

  auto ldA = [&](const char* base, int i) { return *(const s8vec*)(base + aoff + i * 1024); };
  auto ldB = [&](const char* base, int j) { return *(const s8vec*)(base + boff + j * 1024); };

  const int NT = K >> 6;  // K-tiles of 64

  // ---- prologue: stage halves A0,B0,A1,B1,A2,B2,B3 (14 loads) ----
  stageA(0); stageB(0); stageA(1); stageB(1); stageA(2); stageB(2); stageB(3);
  asm volatile("s_waitcnt vmcnt(10)" ::: "memory");  // A0,B0 resident
  __builtin_amdgcn_s_barrier();

  for (int kt = 0; kt < NT; ++kt) {
    const char* Ak0 = (const char*)As + (((2 * kt) & 3) << 14);
    const char* Bk0 = (const char*)Bs + (((2 * kt) & 3) << 14);
    const char* Ak1 = (const char*)As + (((2 * kt + 1) & 3) << 14);
    const char* Bk1 = (const char*)Bs + (((2 * kt + 1) & 3) << 14);
    s8vec a4[4], b4[4];

    // ---------------- P0: (ks0, m-group 0) ----------------
#pragma unroll
    for (int i = 0; i < 4; i++) a4[i] = ldA(Ak0, i);
#pragma unroll
    for (int j = 0; j < 4; j++) b4[j] = ldB(Bk0, j);
    if (kt + 1 < NT) stageA(2 * kt + 3);
    __builtin_amdgcn_s_barrier();
    asm volatile("s_waitcnt lgkmcnt(0)" ::: "memory");
    __builtin_amdgcn_sched_barrier(0);
    __builtin_amdgcn_s_setprio(1);
#pragma unroll
    for (int i = 0; i < 4; i++)
#pragma unroll
      for (int j = 0; j < 4; j++) acc[i][j] = mfma16(a4[i], b4[j], acc[i][j]);
    __builtin_amdgcn_s_setprio(0);
    __builtin_amdgcn_s_barrier();

    // ---------------- P1: (ks0, m-group 1), B reused ----------------
#pragma unroll
    for (int i = 0; i < 4; i++) a4[i] = ldA(Ak0, 4 + i);
    if (kt + 2 < NT) stageB(2 * kt + 4);
    __builtin_amdgcn_s_barrier();
    asm volatile("s_waitcnt lgkmcnt(0)" ::: "memory");
    __builtin_amdgcn_sched_barrier(0);
    __builtin_amdgcn_s_setprio(1);
#pragma unroll
    for (int i = 0; i < 4; i++)
#pragma unroll
      for (int j = 0; j < 4; j++) acc[4 + i][j] = mfma16(a4[i], b4[j], acc[4 + i][j]);
    __builtin_amdgcn_s_setprio(0);
    if (kt < NT - 2)       asm volatile("s_waitcnt vmcnt(10)" ::: "memory");
    else if (kt == NT - 2) asm volatile("s_waitcnt vmcnt(8)" ::: "memory");
    else                   asm volatile("s_waitcnt vmcnt(0)" ::: "memory");
    __builtin_amdgcn_s_barrier();

    // ---------------- P2: (ks1, m-group 0) ----------------
#pragma unroll
    for (int i = 0; i < 4; i++) a4[i] = ldA(Ak1, i);
#pragma unroll
    for (int j = 0; j < 4; j++) b4[j] = ldB(Bk1, j);
    if (kt + 2 < NT) stageA(2 * kt + 4);
    __builtin_amdgcn_s_barrier();
    asm volatile("s_waitcnt lgkmcnt(0)" ::: "memory");
    __builtin_amdgcn_sched_barrier(0);
    __builtin_amdgcn_s_setprio(1);
#pragma unroll
    for (int i = 0; i < 4; i++)
#pragma unroll
      for (int j = 0; j < 4; j++) acc[i][j] = mfma16(a4[i], b4[j], acc[i][j]);
    __builtin_amdgcn_s_setprio(0);
    __builtin_amdgcn_s_barrier();

    // ---------------- P3: (ks1, m-group 1), B reused ----------------
#pragma unroll
    for (int i = 0; i < 4; i++) a4[i] = ldA(Ak1, 4 + i);
    if (kt + 2 < NT) stageB(2 * kt + 5);
    __builtin_amdgcn_s_barrier();
    asm volatile("s_waitcnt lgkmcnt(0)" ::: "memory");
    __builtin_amdgcn_sched_barrier(0);
    __builtin_amdgcn_s_setprio(1);
#pragma unroll
    for (int i = 0; i < 4; i++)
#pragma unroll
      for (int j = 0; j < 4; j++) acc[4 + i][j] = mfma16(a4[i], b4[j], acc[4 + i][j]);
    __builtin_amdgcn_s_setprio(0);
    if (kt + 1 < NT) {
      if (kt < NT - 2) asm volatile("s_waitcnt vmcnt(10)" ::: "memory");
      else             asm volatile("s_waitcnt vmcnt(4)" ::: "memory");
      __builtin_amdgcn_s_barrier();
    }
  }
  epi(acc, wm, wn, lane15, quad);
}

// Fused QKV projection: blockIdx.x selects {Q:0..15, K:16..19, V:20..23}
__launch_bounds__(512, 1)
__global__ void gemm_qkv(const __hip_bfloat16* __restrict__ xb,
                         const __hip_bfloat16* __restrict__ qwb,
                         const __hip_bfloat16* __restrict__ kwb,
                         const __hip_bfloat16* __restrict__ vwb,
                         const float* __restrict__ qb, const float* __restrict__ kb,
                         const float* __restrict__ vb,
                         __hip_bfloat16* __restrict__ qh, __hip_bfloat16* __restrict__ kh,
                         __hip_bfloat16* __restrict__ vth) {
  const int bx = blockIdx.x;
  const long m0 = (long)blockIdx.y << 8;  // 256-row tiles
  int mode; long n0;
  const __hip_bfloat16* Bw; const float* bias;
  if (bx < 16)      { mode = 0; Bw = qwb; bias = qb; n0 = (long)bx << 8; }
  else if (bx < 20) { mode = 1; Bw = kwb; bias = kb; n0 = (long)(bx - 16) << 8; }
  else              { mode = 2; Bw = vwb; bias = vb; n0 = (long)(bx - 20) << 8; }

  gemm_bt_body(xb, Bw, 4096, m0, n0,
    [&](f4vec (&acc)[8][4], int wm, int wn, int lane15, int quad) {
      float bv[4];
#pragma unroll
      for (int j = 0; j < 4; j++) bv[j] = bias[n0 + wn + j * 16 + lane15];
#pragma unroll
      for (int i = 0; i < 8; i++)
#pragma unroll
        for (int j = 0; j < 4; j++)
#pragma unroll
          for (int r = 0; r < 4; r++) {
            const long gm = m0 + wm + i * 16 + (quad << 2) + r;
            const long gn = n0 + wn + j * 16 + lane15;
            const float v = acc[i][j][r] + bv[j];
            const long bb = gm >> 11, ss = gm & 2047;
            const long hh = gn >> 7, dd = gn & 127;
            const __hip_bfloat16 hv = __float2bfloat16(v);
            if (mode == 0)
              qh[(((bb * Hn + hh) * Sn + ss) << 7) + dd] = hv;
            else if (mode == 1)
              kh[(((bb * KVn + hh) * Sn + ss) << 7) + dd] = hv;
            else
              vth[((bb * KVn + hh) * Dn + dd) * (long)Sn + ss] = hv;
          }
    });
}

// O projection: fp32 out + bias
__launch_bounds__(512, 1)
__global__ void gemm_out(const __hip_bfloat16* __restrict__ A,
                         const __hip_bfloat16* __restrict__ Bw,
                         const float* __restrict__ bias, float* __restrict__ Cout) {
  const long m0 = (long)blockIdx.y << 8;
  const long n0 = (long)blockIdx.x << 8;
  gemm_bt_body(A, Bw, 4096, m0, n0,
    [&](f4vec (&acc)[8][4], int wm, int wn, int lane15, int quad) {
      float bv[4];
#pragma unroll
      for (int j = 0; j < 4; j++) bv[j] = bias[n0 + wn + j * 16 + lane15];
#pragma unroll
      for (int i = 0; i < 8; i++)
#pragma unroll
        for (int j = 0; j < 4; j++)
#pragma unroll
          for (int r = 0; r < 4; r++) {
            const long gm = m0 + wm + i * 16 + (quad << 2) + r;
            const long gn = n0 + wn + j * 16 + lane15;
            Cout[gm * HIDn + gn] = acc[i][j][r] + bv[j];
          }
    });
}

// ---------------------------------------------------------------------------
// Fused causal GQA flash attention, v3 (unchanged this round).
// ---------------------------------------------------------------------------
__launch_bounds__(256, 2)
__global__ void attn_fused(const __hip_bfloat16* __restrict__ Qh,
                           const __hip_bfloat16* __restrict__ Kh,
                           const __hip_bfloat16* __restrict__ Vt,
                           __hip_bfloat16* __restrict__ Oa) {
  __shared__ __hip_bfloat16 Ks[2][64 * 128];
  __shared__ __hip_bfloat16 Vs[2][128 * 64];   // [d][s] tiles
  __shared__ __hip_bfloat16 Ps[4][32 * 64];    // per-wave P

  const int pair = blockIdx.x;  // 0..7
  const int h = blockIdx.y;     // 0..31
  const int b = blockIdx.z;     // 0..1
  const int kv = h & 7;

  const int t = threadIdx.x, w = t >> 6, l = t & 63;
  const int lane15 = l & 15, quad = l >> 4;
  const int swz = lane15 & 7;

  const char* KgB = (const char*)(Kh + ((long)(b * KVn + kv)) * Sn * Dn);
  const char* VgB = (const char*)(Vt + ((long)(b * KVn + kv)) * Dn * (long)Sn);

  // staging address swizzle (global side; LDS dest is fixed base+lane*16)
  const int kc = (t & 15) ^ ((t >> 4) & 7);
  const char* kg_base = KgB + (t >> 4) * 256 + kc * 16;
  const int vc = (t & 7) ^ ((t >> 3) & 7);
  const char* vg_base = VgB + (t >> 3) * (size_t)(Sn * 2) + vc * 16;

  const short* Psh = (const short*)Ps[w];
  short* Psw = (short*)Ps[w];
  const float cscale = 0.08838834764831845f * 1.4426950408889634f;  // 1/sqrt(D)*log2e
  const float coff = -8.0f * 1.4426950408889634f;                   // safe shift

  for (int ph = 0; ph < 2; ph++) {
    const int qt = ph ? (15 - pair) : pair;

    // Q fragments direct from global, held in registers for the whole phase
    s8vec aq[2][4];
    {
      const short* Qgs = (const short*)(Qh + (((long)(b * Hn + h)) * Sn + qt * 128) * (long)Dn);
#pragma unroll
      for (int i = 0; i < 2; i++)
#pragma unroll
        for (int kk = 0; kk < 4; kk++)
          aq[i][kk] = *(const s8vec*)(Qgs + (w * 32 + i * 16 + lane15) * 128 + kk * 32 + (quad << 3));
    }
    float lsum[2][4] = {};
    f4vec acco[2][8] = {};

    __syncthreads();  // protect buffers from previous phase's readers
    {  // stage tile 0 -> buf 0
      char* lk = (char*)Ks[0] + (w << 10);
      char* lv = (char*)Vs[0] + (w << 10);
#pragma unroll
      for (int i = 0; i < 4; i++) async_ld16(kg_base + i * 4096, lk + i * 4096);
#pragma unroll
      for (int i = 0; i < 4; i++) async_ld16(vg_base + (size_t)i * 32 * Sn * 2, lv + i * 4096);
    }

    const int n_kt = 2 * qt + 2, full_kt = 2 * qt;
    for (int kt = 0; kt < n_kt; kt++) {
      const int cur = kt & 1;
      __syncthreads();  // drains vmcnt(0): tile kt resident; prev compute done
      if (kt + 1 < n_kt) {  // prefetch tile kt+1 into the other buffer
        char* lk = (char*)Ks[cur ^ 1] + (w << 10);
        char* lv = (char*)Vs[cur ^ 1] + (w << 10);
        const char* kg = kg_base + (size_t)(kt + 1) * 16384;
        const char* vg = vg_base + (size_t)(kt + 1) * 128;
#pragma unroll
        for (int i = 0; i < 4; i++) async_ld16(kg + i * 4096, lk + i * 4096);
#pragma unroll
        for (int i = 0; i < 4; i++) async_ld16(vg + (size_t)i * 32 * Sn * 2, lv + i * 4096);
      }
      const short* Ksh = (const short*)Ks[cur];
      const short* Vsh = (const short*)Vs[cur];
      const bool need_mask = (kt >= full_kt);

      // ---- S = Q K^T (j-column groups), softmax immediately ----
#pragma unroll
      for (int j = 0; j < 4; j++) {
        f4vec as0 = {}, as1 = {};
#pragma unroll
        for (int kk = 0; kk < 4; kk++) {
          const s8vec bk = *(const s8vec*)(Ksh + (j * 16 + lane15) * 128 + (((quad + 4 * kk) ^ swz) << 3));
          as0 = mfma16(aq[0][kk], bk, as0);
          as1 = mfma16(aq[1][kk], bk, as1);
        }
        const int pc = j * 16 + lane15;
        const int kcol = kt * 64 + pc;
#pragma unroll
        for (int i = 0; i < 2; i++) {
#pragma unroll
          for (int r = 0; r < 4; r++) {
            const int pr = i * 16 + (quad << 2) + r;
            float sv = (i ? as1[r] : as0[r]) * cscale + coff;
            if (need_mask) {
              const int qr = qt * 128 + w * 32 + pr;
              if (kcol > qr) sv = -1000000.0f;  // exp2 -> 0
            }
            const float p = __builtin_amdgcn_exp2f(sv);
            lsum[i][r] += p;
            Psw[pr * 64 + ((((pc >> 3) ^ (pr & 7)) << 3) | (pc & 7))] =
                __bfloat16_as_short(__float2bfloat16(p));
          }
        }
      }
      asm volatile("s_waitcnt lgkmcnt(0)" ::: "memory");

      // ---- O += P V ----
#pragma unroll
      for (int kk = 0; kk < 2; kk++) {
        s8vec ap[2], bv8[8];
#pragma unroll
        for (int i = 0; i < 2; i++)
          ap[i] = *(const s8vec*)(Psh + (i * 16 + lane15) * 64 + (((quad + 4 * kk) ^ swz) << 3));
#pragma unroll
        for (int j = 0; j < 8; j++)
          bv8[j] = *(const s8vec*)(Vsh + (j * 16 + lane15) * 64 + (((quad + 4 * kk) ^ swz) << 3));
#pragma unroll
        for (int i = 0; i < 2; i++)
#pragma unroll
          for (int j = 0; j < 8; j++)
            acco[i][j] = mfma16(ap[i], bv8[j], acco[i][j]);
      }
    }

    // epilogue: reduce lsum across the 16 lane15 lanes, write O
#pragma unroll
    for (int i = 0; i < 2; i++)
#pragma unroll
      for (int r = 0; r < 4; r++) {
        float s = lsum[i][r];
#pragma unroll
        for (int d = 1; d < 16; d <<= 1) s += __shfl_xor(s, d);
        lsum[i][r] = 1.0f / s;
      }
#pragma unroll
    for (int i = 0; i < 2; i++) {
#pragma unroll
      for (int r = 0; r < 4; r++) {
        const int row = qt * 128 + w * 32 + i * 16 + (quad << 2) + r;
        const long base = ((long)b * Sn + row) * HIDn + h * Dn;
#pragma unroll
        for (int j = 0; j < 8; j++)
          Oa[base + j * 16 + lane15] = __float2bfloat16(acco[i][j][r] * lsum[i][r]);
      }
    }
  }
}

// ---------------------------------------------------------------------------
extern "C" void kernel_launch(void* const* d_in, const int* in_sizes, int n_in,
                              void* d_out, int out_size, void* d_ws, size_t ws_size,
                              hipStream_t stream) {
  const float* x   = (const float*)d_in[0];
  const float* q_w = (const float*)d_in[2];
  const float* q_b = (const float*)d_in[3];
  const float* k_w = (const float*)d_in[4];
  const float* k_b = (const float*)d_in[5];
  const float* v_w = (const float*)d_in[6];
  const float* v_b = (const float*)d_in[7];
  const float* o_w = (const float*)d_in[8];
  const float* o_b = (const float*)d_in[9];

  char* ws = (char*)d_ws;
  size_t off = 0;
  auto nxt = [&](size_t bytes) { char* p = ws + off; off += bytes; return p; };
  __hip_bfloat16* xb  = (__hip_bfloat16*)nxt(33554432);
  __hip_bfloat16* qwb = (__hip_bfloat16*)nxt(33554432);
  __hip_bfloat16* kwb = (__hip_bfloat16*)nxt(8388608);
  __hip_bfloat16* vwb = (__hip_bfloat16*)nxt(8388608);
  __hip_bfloat16* owb = (__hip_bfloat16*)nxt(33554432);
  __hip_bfloat16* qh  = (__hip_bfloat16*)nxt(33554432);  // [B,H,S,D]
  __hip_bfloat16* kh  = (__hip_bfloat16*)nxt(8388608);   // [B,KV,S,D]
  __hip_bfloat16* vth = (__hip_bfloat16*)nxt(8388608);   // [B,KV,D,S]
  __hip_bfloat16* at  = (__hip_bfloat16*)nxt(33554432);  // [B,S,HID]
  (void)ws_size; (void)in_sizes; (void)n_in; (void)out_size;

  cvt_all<<<57344, 256, 0, stream>>>(x, q_w, k_w, v_w, o_w, xb, qwb, kwb, vwb, owb);
  gemm_qkv<<<dim3(24, 16), 512, 0, stream>>>(xb, qwb, kwb, vwb, q_b, k_b, v_b, qh, kh, vth);
  attn_fused<<<dim3(8, 32, 2), 256, 0, stream>>>(qh, kh, vth, at);
  gemm_out<<<dim3(16, 16), 512, 0, stream>>>(at, owb, o_b, (float*)d_out);
}

// Round 4
// 718.317 us; speedup vs baseline: 1.0522x; 1.0522x over previous
//
#include <hip/hip_runtime.h>
#include <hip/hip_bf16.h>
#include <cstdint>

typedef __attribute__((ext_vector_type(8))) short s8vec;
typedef __attribute__((ext_vector_type(4))) float f4vec;

#define DEV __device__ __forceinline__

constexpr int Bn = 2, Sn = 2048, HIDn = 4096, Hn = 32, KVn = 8, Dn = 128;

typedef const __attribute__((address_space(1))) void gvoid_t;
typedef __attribute__((address_space(3))) void lvoid_t;

DEV void async_ld16(const void* g, void* l) {
  __builtin_amdgcn_global_load_lds((gvoid_t*)g, (lvoid_t*)l, 16, 0, 0);
}

DEV f4vec mfma16(s8vec a, s8vec b, f4vec c) {
  return __builtin_amdgcn_mfma_f32_16x16x32_bf16(a, b, c, 0, 0, 0);
}

// ---------------------------------------------------------------------------
// Fused fp32 -> bf16 cast for all 5 tensors in one launch.
// ---------------------------------------------------------------------------
__global__ void cvt_all(const float* __restrict__ x, const float* __restrict__ qw,
                        const float* __restrict__ kw, const float* __restrict__ vw,
                        const float* __restrict__ ow,
                        __hip_bfloat16* __restrict__ xb, __hip_bfloat16* __restrict__ qwb,
                        __hip_bfloat16* __restrict__ kwb, __hip_bfloat16* __restrict__ vwb,
                        __hip_bfloat16* __restrict__ owb) {
  const int i = blockIdx.x * 256 + threadIdx.x;
  const float* src; __hip_bfloat16* dst; int off;
  if (i < 4194304)       { src = x;  dst = xb;  off = i; }
  else if (i < 8388608)  { src = qw; dst = qwb; off = i - 4194304; }
  else if (i < 9437184)  { src = kw; dst = kwb; off = i - 8388608; }
  else if (i < 10485760) { src = vw; dst = vwb; off = i - 9437184; }
  else                   { src = ow; dst = owb; off = i - 10485760; }
  float4 f = ((const float4*)src)[off];
  union { __hip_bfloat16 h[4]; uint2 u; } cv;
  cv.h[0] = __float2bfloat16(f.x);
  cv.h[1] = __float2bfloat16(f.y);
  cv.h[2] = __float2bfloat16(f.z);
  cv.h[3] = __float2bfloat16(f.w);
  ((uint2*)dst)[off] = cv.u;
}

// ---------------------------------------------------------------------------
// GEMM-BT core v5: C[M,N] = A[M,K]*B[N,K]^T.  MINIMAL-BARRIER schedule.
// 256x256 tile, BK=64, 512 threads = 8 waves (2M x 4N), per-wave 128x64 out.
// LDS: 2 double-buffers of full K-tiles (A 32KB + B 32KB per buf = 128 KB).
// Per K-tile (ONLY 2 barriers):
//   24 ds_read_b128 (ALL fragments, both k-steps)    <- one contended phase
//   lgkmcnt(0) + sched_barrier + s_barrier           <- buffer provably free
//   stage tile tau+2 into freed buffer (8 gload_lds) <- 2-tile latency budget
//   setprio(1); 64 MFMA; setprio(0)                  <- absorbs staging writes
//   vmcnt(8) counted (tau+1 resident, tau+2 in flight; never drains) + barrier
// Cycle model per K-tile/CU: 1755 (LDS reads) + 2061 (MFMA) + ~200 ≈ 4016 cy
// -> ~51% per-tile vs 36% of the 4-phase schedule (8 barriers serialized).
// Swizzle both-sides (round-2-verified 0-conflict class): physical 16B chunk
// p of row r holds logical chunk p ^ (r&7); stager pre-XORs the global
// column; reader XORs its (quad|ks) chunk with lane15&7.
// ---------------------------------------------------------------------------
template <typename EpiF>
DEV void gemm_bt_body(const __hip_bfloat16* A, const __hip_bfloat16* Bw, int K,
                      long m0, long n0, EpiF epi) {
  __shared__ __hip_bfloat16 As[2][256 * 64];
  __shared__ __hip_bfloat16 Bs[2][256 * 64];
  const int t = threadIdx.x;       // 0..511
  const int w = t >> 6, l = t & 63;
  const int lane15 = l & 15, quad = l >> 4;
  const int wm = (w >> 2) << 7;    // 0,128
  const int wn = (w & 3) << 6;     // 0,64,128,192

  f4vec acc[8][4] = {};

  // ---- staging addressing ----
  // thread t, sweep s (0..3): LDS byte t*16 + s*8192 = row ((t>>3)+64s) of
  // 128B, physical chunk t&7.  Source pre-swizzled: logical chunk
  // (t&7)^(row&7) = (t&7)^((t>>3)&7)  (64s ≡ 0 mod 8).
  const int srow = t >> 3;                         // 0..63
  const int schunk = (t & 7) ^ (srow & 7);
  const __hip_bfloat16* gA = A + (m0 + srow) * (long)K + (schunk << 3);
  const __hip_bfloat16* gB = Bw + (n0 + srow) * (long)K + (schunk << 3);
  const long r64K = (long)K << 6;  // 64 rows of K elems

  auto stage = [&](int buf, int kt) {
    char* la = (char*)As[buf] + t * 16;
    char* lb = (char*)Bs[buf] + t * 16;
    const long ko = (long)kt << 6;
#pragma unroll
    for (int s = 0; s < 4; s++) async_ld16(gA + (long)s * r64K + ko, la + s * 8192);
#pragma unroll
    for (int s = 0; s < 4; s++) async_ld16(gB + (long)s * r64K + ko, lb + s * 8192);
  };

  // ---- fragment read addressing ----
  // row = wm/wn + i*16 + lane15 (row&7 = lane15&7); k-chunk = ks*4+quad;
  // byte = row*128 + ((kchunk ^ (row&7))<<4).  ks1 = ks0 byte ^ 64.
  const int co = (quad ^ (lane15 & 7)) << 4;
  const int aoff = (wm + lane15) * 128 + co;
  const int boff = (wn + lane15) * 128 + co;

  const int NT = K >> 6;

  stage(0, 0);
  stage(1, 1);
  asm volatile("s_waitcnt vmcnt(8)" ::: "memory");  // tile 0 resident
  __builtin_amdgcn_s_barrier();
  __builtin_amdgcn_sched_barrier(0);

  for (int tau = 0; tau < NT; ++tau) {
    const char* Ab = (const char*)As[tau & 1];
    const char* Bb = (const char*)Bs[tau & 1];
    s8vec a0[8], a1[8], b0[4], b1[4];
#pragma unroll
    for (int i = 0; i < 8; i++) {
      a0[i] = *(const s8vec*)(Ab + (aoff + i * 2048));
      a1[i] = *(const s8vec*)(Ab + ((aoff + i * 2048) ^ 64));
    }
#pragma unroll
    for (int j = 0; j < 4; j++) {
      b0[j] = *(const s8vec*)(Bb + (boff + j * 2048));
      b1[j] = *(const s8vec*)(Bb + ((boff + j * 2048) ^ 64));
    }
    asm volatile("s_waitcnt lgkmcnt(0)" ::: "memory");
    __builtin_amdgcn_sched_barrier(0);
    __builtin_amdgcn_s_barrier();            // all waves done reading buf[tau&1]
    __builtin_amdgcn_sched_barrier(0);
    if (tau + 2 < NT) stage(tau & 1, tau + 2);  // overwrite freed buffer (async)
    __builtin_amdgcn_s_setprio(1);
#pragma unroll
    for (int i = 0; i < 8; i++)
#pragma unroll
      for (int j = 0; j < 4; j++) acc[i][j] = mfma16(a0[i], b0[j], acc[i][j]);
#pragma unroll
    for (int i = 0; i < 8; i++)
#pragma unroll
      for (int j = 0; j < 4; j++) acc[i][j] = mfma16(a1[i], b1[j], acc[i][j]);
    __builtin_amdgcn_s_setprio(0);
    if (tau + 2 < NT) {
      asm volatile("s_waitcnt vmcnt(8)" ::: "memory");  // tau+1 resident
      __builtin_amdgcn_s_barrier();
      __builtin_amdgcn_sched_barrier(0);
    } else if (tau + 1 < NT) {
      asm volatile("s_waitcnt vmcnt(0)" ::: "memory");
      __builtin_amdgcn_s_barrier();
      __builtin_amdgcn_sched_barrier(0);
    }
  }
  epi(acc, wm, wn, lane15, quad);
}

// Fused QKV projection: blockIdx.x selects {Q:0..15, K:16..19, V:20..23}
__launch_bounds__(512, 2)
__global__ void gemm_qkv(const __hip_bfloat16* __restrict__ xb,
                         const __hip_bfloat16* __restrict__ qwb,
                         const __hip_bfloat16* __restrict__ kwb,
                         const __hip_bfloat16* __restrict__ vwb,
                         const float* __restrict__ qb, const float* __restrict__ kb,
                         const float* __restrict__ vb,
                         __hip_bfloat16* __restrict__ qh, __hip_bfloat16* __restrict__ kh,
                         __hip_bfloat16* __restrict__ vth) {
  const int bx = blockIdx.x;
  const long m0 = (long)blockIdx.y << 8;  // 256-row tiles
  int mode; long n0;
  const __hip_bfloat16* Bw; const float* bias;
  if (bx < 16)      { mode = 0; Bw = qwb; bias = qb; n0 = (long)bx << 8; }
  else if (bx < 20) { mode = 1; Bw = kwb; bias = kb; n0 = (long)(bx - 16) << 8; }
  else              { mode = 2; Bw = vwb; bias = vb; n0 = (long)(bx - 20) << 8; }

  gemm_bt_body(xb, Bw, 4096, m0, n0,
    [&](f4vec (&acc)[8][4], int wm, int wn, int lane15, int quad) {
      float bv[4];
#pragma unroll
      for (int j = 0; j < 4; j++) bv[j] = bias[n0 + wn + j * 16 + lane15];
#pragma unroll
      for (int i = 0; i < 8; i++)
#pragma unroll
        for (int j = 0; j < 4; j++)
#pragma unroll
          for (int r = 0; r < 4; r++) {
            const long gm = m0 + wm + i * 16 + (quad << 2) + r;
            const long gn = n0 + wn + j * 16 + lane15;
            const float v = acc[i][j][r] + bv[j];
            const long bb = gm >> 11, ss = gm & 2047;
            const long hh = gn >> 7, dd = gn & 127;
            const __hip_bfloat16 hv = __float2bfloat16(v);
            if (mode == 0)
              qh[(((bb * Hn + hh) * Sn + ss) << 7) + dd] = hv;
            else if (mode == 1)
              kh[(((bb * KVn + hh) * Sn + ss) << 7) + dd] = hv;
            else
              vth[((bb * KVn + hh) * Dn + dd) * (long)Sn + ss] = hv;
          }
    });
}

// O projection: fp32 out + bias.  16x16 = 256 blocks = ONE exact round.
__launch_bounds__(512, 2)
__global__ void gemm_out(const __hip_bfloat16* __restrict__ A,
                         const __hip_bfloat16* __restrict__ Bw,
                         const float* __restrict__ bias, float* __restrict__ Cout) {
  const long m0 = (long)blockIdx.y << 8;
  const long n0 = (long)blockIdx.x << 8;
  gemm_bt_body(A, Bw, 4096, m0, n0,
    [&](f4vec (&acc)[8][4], int wm, int wn, int lane15, int quad) {
      float bv[4];
#pragma unroll
      for (int j = 0; j < 4; j++) bv[j] = bias[n0 + wn + j * 16 + lane15];
#pragma unroll
      for (int i = 0; i < 8; i++)
#pragma unroll
        for (int j = 0; j < 4; j++)
#pragma unroll
          for (int r = 0; r < 4; r++) {
            const long gm = m0 + wm + i * 16 + (quad << 2) + r;
            const long gn = n0 + wn + j * 16 + lane15;
            Cout[gm * HIDn + gn] = acc[i][j][r] + bv[j];
          }
    });
}

// ---------------------------------------------------------------------------
// Fused causal GQA flash attention, v3 (unchanged this round).
// ---------------------------------------------------------------------------
__launch_bounds__(256, 2)
__global__ void attn_fused(const __hip_bfloat16* __restrict__ Qh,
                           const __hip_bfloat16* __restrict__ Kh,
                           const __hip_bfloat16* __restrict__ Vt,
                           __hip_bfloat16* __restrict__ Oa) {
  __shared__ __hip_bfloat16 Ks[2][64 * 128];
  __shared__ __hip_bfloat16 Vs[2][128 * 64];   // [d][s] tiles
  __shared__ __hip_bfloat16 Ps[4][32 * 64];    // per-wave P

  const int pair = blockIdx.x;  // 0..7
  const int h = blockIdx.y;     // 0..31
  const int b = blockIdx.z;     // 0..1
  const int kv = h & 7;

  const int t = threadIdx.x, w = t >> 6, l = t & 63;
  const int lane15 = l & 15, quad = l >> 4;
  const int swz = lane15 & 7;

  const char* KgB = (const char*)(Kh + ((long)(b * KVn + kv)) * Sn * Dn);
  const char* VgB = (const char*)(Vt + ((long)(b * KVn + kv)) * Dn * (long)Sn);

  // staging address swizzle (global side; LDS dest is fixed base+lane*16)
  const int kc = (t & 15) ^ ((t >> 4) & 7);
  const char* kg_base = KgB + (t >> 4) * 256 + kc * 16;
  const int vc = (t & 7) ^ ((t >> 3) & 7);
  const char* vg_base = VgB + (t >> 3) * (size_t)(Sn * 2) + vc * 16;

  const short* Psh = (const short*)Ps[w];
  short* Psw = (short*)Ps[w];
  const float cscale = 0.08838834764831845f * 1.4426950408889634f;  // 1/sqrt(D)*log2e
  const float coff = -8.0f * 1.4426950408889634f;                   // safe shift

  for (int ph = 0; ph < 2; ph++) {
    const int qt = ph ? (15 - pair) : pair;

    // Q fragments direct from global, held in registers for the whole phase
    s8vec aq[2][4];
    {
      const short* Qgs = (const short*)(Qh + (((long)(b * Hn + h)) * Sn + qt * 128) * (long)Dn);
#pragma unroll
      for (int i = 0; i < 2; i++)
#pragma unroll
        for (int kk = 0; kk < 4; kk++)
          aq[i][kk] = *(const s8vec*)(Qgs + (w * 32 + i * 16 + lane15) * 128 + kk * 32 + (quad << 3));
    }
    float lsum[2][4] = {};
    f4vec acco[2][8] = {};

    __syncthreads();  // protect buffers from previous phase's readers
    {  // stage tile 0 -> buf 0
      char* lk = (char*)Ks[0] + (w << 10);
      char* lv = (char*)Vs[0] + (w << 10);
#pragma unroll
      for (int i = 0; i < 4; i++) async_ld16(kg_base + i * 4096, lk + i * 4096);
#pragma unroll
      for (int i = 0; i < 4; i++) async_ld16(vg_base + (size_t)i * 32 * Sn * 2, lv + i * 4096);
    }

    const int n_kt = 2 * qt + 2, full_kt = 2 * qt;
    for (int kt = 0; kt < n_kt; kt++) {
      const int cur = kt & 1;
      __syncthreads();  // drains vmcnt(0): tile kt resident; prev compute done
      if (kt + 1 < n_kt) {  // prefetch tile kt+1 into the other buffer
        char* lk = (char*)Ks[cur ^ 1] + (w << 10);
        char* lv = (char*)Vs[cur ^ 1] + (w << 10);
        const char* kg = kg_base + (size_t)(kt + 1) * 16384;
        const char* vg = vg_base + (size_t)(kt + 1) * 128;
#pragma unroll
        for (int i = 0; i < 4; i++) async_ld16(kg + i * 4096, lk + i * 4096);
#pragma unroll
        for (int i = 0; i < 4; i++) async_ld16(vg + (size_t)i * 32 * Sn * 2, lv + i * 4096);
      }
      const short* Ksh = (const short*)Ks[cur];
      const short* Vsh = (const short*)Vs[cur];
      const bool need_mask = (kt >= full_kt);

      // ---- S = Q K^T (j-column groups), softmax immediately ----
#pragma unroll
      for (int j = 0; j < 4; j++) {
        f4vec as0 = {}, as1 = {};
#pragma unroll
        for (int kk = 0; kk < 4; kk++) {
          const s8vec bk = *(const s8vec*)(Ksh + (j * 16 + lane15) * 128 + (((quad + 4 * kk) ^ swz) << 3));
          as0 = mfma16(aq[0][kk], bk, as0);
          as1 = mfma16(aq[1][kk], bk, as1);
        }
        const int pc = j * 16 + lane15;
        const int kcol = kt * 64 + pc;
#pragma unroll
        for (int i = 0; i < 2; i++) {
#pragma unroll
          for (int r = 0; r < 4; r++) {
            const int pr = i * 16 + (quad << 2) + r;
            float sv = (i ? as1[r] : as0[r]) * cscale + coff;
            if (need_mask) {
              const int qr = qt * 128 + w * 32 + pr;
              if (kcol > qr) sv = -1000000.0f;  // exp2 -> 0
            }
            const float p = __builtin_amdgcn_exp2f(sv);
            lsum[i][r] += p;
            Psw[pr * 64 + ((((pc >> 3) ^ (pr & 7)) << 3) | (pc & 7))] =
                __bfloat16_as_short(__float2bfloat16(p));
          }
        }
      }
      asm volatile("s_waitcnt lgkmcnt(0)" ::: "memory");

      // ---- O += P V ----
#pragma unroll
      for (int kk = 0; kk < 2; kk++) {
        s8vec ap[2], bv8[8];
#pragma unroll
        for (int i = 0; i < 2; i++)
          ap[i] = *(const s8vec*)(Psh + (i * 16 + lane15) * 64 + (((quad + 4 * kk) ^ swz) << 3));
#pragma unroll
        for (int j = 0; j < 8; j++)
          bv8[j] = *(const s8vec*)(Vsh + (j * 16 + lane15) * 64 + (((quad + 4 * kk) ^ swz) << 3));
#pragma unroll
        for (int i = 0; i < 2; i++)
#pragma unroll
          for (int j = 0; j < 8; j++)
            acco[i][j] = mfma16(ap[i], bv8[j], acco[i][j]);
      }
    }

    // epilogue: reduce lsum across the 16 lane15 lanes, write O
#pragma unroll
    for (int i = 0; i < 2; i++)
#pragma unroll
      for (int r = 0; r < 4; r++) {
        float s = lsum[i][r];
#pragma unroll
        for (int d = 1; d < 16; d <<= 1) s += __shfl_xor(s, d);
        lsum[i][r] = 1.0f / s;
      }
#pragma unroll
    for (int i = 0; i < 2; i++) {
#pragma unroll
      for (int r = 0; r < 4; r++) {
        const int row = qt * 128 + w * 32 + i * 16 + (quad << 2) + r;
        const long base = ((long)b * Sn + row) * HIDn + h * Dn;
#pragma unroll
        for (int j = 0; j < 8; j++)
          Oa[base + j * 16 + lane15] = __float2bfloat16(acco[i][j][r] * lsum[i][r]);
      }
    }
  }
}

// ---------------------------------------------------------------------------
extern "C" void kernel_launch(void* const* d_in, const int* in_sizes, int n_in,
                              void* d_out, int out_size, void* d_ws, size_t ws_size,
                              hipStream_t stream) {
  const float* x   = (const float*)d_in[0];
  const float* q_w = (const float*)d_in[2];
  const float* q_b = (const float*)d_in[3];
  const float* k_w = (const float*)d_in[4];
  const float* k_b = (const float*)d_in[5];
  const float* v_w = (const float*)d_in[6];
  const float* v_b = (const float*)d_in[7];
  const float* o_w = (const float*)d_in[8];
  const float* o_b = (const float*)d_in[9];

  char* ws = (char*)d_ws;
  size_t off = 0;
  auto nxt = [&](size_t bytes) { char* p = ws + off; off += bytes; return p; };
  __hip_bfloat16* xb  = (__hip_bfloat16*)nxt(33554432);
  __hip_bfloat16* qwb = (__hip_bfloat16*)nxt(33554432);
  __hip_bfloat16* kwb = (__hip_bfloat16*)nxt(8388608);
  __hip_bfloat16* vwb = (__hip_bfloat16*)nxt(8388608);
  __hip_bfloat16* owb = (__hip_bfloat16*)nxt(33554432);
  __hip_bfloat16* qh  = (__hip_bfloat16*)nxt(33554432);  // [B,H,S,D]
  __hip_bfloat16* kh  = (__hip_bfloat16*)nxt(8388608);   // [B,KV,S,D]
  __hip_bfloat16* vth = (__hip_bfloat16*)nxt(8388608);   // [B,KV,D,S]
  __hip_bfloat16* at  = (__hip_bfloat16*)nxt(33554432);  // [B,S,HID]
  (void)ws_size; (void)in_sizes; (void)n_in; (void)out_size;

  cvt_all<<<57344, 256, 0, stream>>>(x, q_w, k_w, v_w, o_w, xb, qwb, kwb, vwb, owb);
  gemm_qkv<<<dim3(24, 16), 512, 0, stream>>>(xb, qwb, kwb, vwb, q_b, k_b, v_b, qh, kh, vth);
  attn_fused<<<dim3(8, 32, 2), 256, 0, stream>>>(qh, kh, vth, at);
  gemm_out<<<dim3(16, 16), 512, 0, stream>>>(at, owb, o_b, (float*)d_out);
}